// Round 2
// baseline (27857.803 us; speedup 1.0000x reference)
//
#include <hip/hip_runtime.h>

typedef unsigned short u16;
typedef float f32x4 __attribute__((ext_vector_type(4)));
typedef short bf16x8 __attribute__((ext_vector_type(8)));

// ---------- bf16 helpers ----------
static __device__ __forceinline__ float bf2f(u16 u) {
  return __uint_as_float(((unsigned)u) << 16);
}
static __device__ __forceinline__ u16 f2bf(float f) {
  unsigned u = __float_as_uint(f);
  u += 0x7fffu + ((u >> 16) & 1u);  // RNE
  return (u16)(u >> 16);
}
static __device__ __forceinline__ float sigmoidf_(float x) {
  return 1.f / (1.f + __expf(-x));
}

#define VOCAB 32000
#define EMBED 512
#define HIDDEN 1024
#define BATCH 64
#define SEQ 512
#define G4H 4096
#define NBLK 256  // persistent-kernel grid

// =====================================================================
// Phase A: xp[t][b][g] = emb_table[x[b][t]] . W_ih[g] + b_ih[g] + b_hh[g]
// (layout [t*64+b][g] so phase B's per-step slice is contiguous-ish)
// =====================================================================
__global__ __launch_bounds__(256) void phaseA(
    const int* __restrict__ x, const float* __restrict__ emb,
    const float* __restrict__ Wih, const float* __restrict__ bih,
    const float* __restrict__ bhh, u16* __restrict__ xp) {
  __shared__ float As[32][65];
  __shared__ float Bs[32][65];
  __shared__ int rows[64];
  const int t = threadIdx.x;
  const int bx = blockIdx.x, by = blockIdx.y;
  if (t < 64) rows[t] = x[by * 64 + t];
  __syncthreads();
  const int tx = t & 15, ty = t >> 4;
  float acc[4][4];
#pragma unroll
  for (int i = 0; i < 4; ++i)
#pragma unroll
    for (int j = 0; j < 4; ++j) acc[i][j] = 0.f;

  for (int k0 = 0; k0 < EMBED; k0 += 32) {
#pragma unroll
    for (int i = 0; i < 8; ++i) {
      int e = t + i * 256;
      int m = e >> 5, k = e & 31;
      As[k][m] = emb[(size_t)rows[m] * EMBED + k0 + k];
      Bs[k][m] = Wih[((size_t)bx * 64 + m) * EMBED + k0 + k];
    }
    __syncthreads();
#pragma unroll
    for (int kk = 0; kk < 32; ++kk) {
      float a[4], b[4];
#pragma unroll
      for (int i = 0; i < 4; ++i) a[i] = As[kk][ty * 4 + i];
#pragma unroll
      for (int j = 0; j < 4; ++j) b[j] = Bs[kk][tx * 4 + j];
#pragma unroll
      for (int i = 0; i < 4; ++i)
#pragma unroll
        for (int j = 0; j < 4; ++j) acc[i][j] = fmaf(a[i], b[j], acc[i][j]);
    }
    __syncthreads();
  }
#pragma unroll
  for (int i = 0; i < 4; ++i) {
    const int gm = by * 64 + ty * 4 + i;  // gm = b*SEQ + t
    const int bb = gm >> 9, tt = gm & 511;
#pragma unroll
    for (int j = 0; j < 4; ++j) {
      const int gn = bx * 64 + tx * 4 + j;
      float v = acc[i][j] + bih[gn] + bhh[gn];
      xp[((size_t)tt * 64 + bb) * G4H + gn] = f2bf(v);
    }
  }
}

// =====================================================================
// Persistent LSTM: all 512 steps in ONE cooperative kernel.
// 256 blocks x 256 thr (4 waves). Block owns 4 hidden units (16 gate
// rows). W_hh rows live in VGPRs as MFMA A-frags (bf16 hi+lo split) for
// the whole sequence. Waves K-split 4 x 256. h double-buffered in
// global, layout h[b][k] bf16. c stays in registers. Grid barrier via
// device-scope atomics each step.
// MFMA 16x16x32 bf16 layouts: A: lane l -> A[m=l&15][k=(l>>4)*8+j];
// B: lane l -> B[k=(l>>4)*8+j][n=l&15]; D: col=lane&15, row=(l>>4)*4+r.
// =====================================================================
__global__ __launch_bounds__(256) void lstm_steps(
    const u16* __restrict__ xp, const float* __restrict__ Whh,
    u16* __restrict__ h0, u16* __restrict__ h1, unsigned* __restrict__ cnt) {
  __shared__ float ps[4][64][17];   // [wave][col=b][row=m], padded
  __shared__ float xps[4][4][64];   // [gate][uoff][b]
  const int t = threadIdx.x;
  const int wave = t >> 6;
  const int l = t & 63;
  const int u0 = blockIdx.x * 4;
  const int m = l & 15;   // D-row index: gate = m>>2, uoff = m&3
  const int kg = l >> 4;  // k-group
  const int wrow = (m >> 2) * HIDDEN + u0 + (m & 3);
  const int kbase = wave * 256;

  // ---- load W_hh A-fragments once (bf16 hi + residual lo) ----
  bf16x8 awh[8], awl[8];
#pragma unroll
  for (int kf = 0; kf < 8; ++kf) {
    const float* wp = Whh + (size_t)wrow * HIDDEN + kbase + kf * 32 + kg * 8;
#pragma unroll
    for (int j = 0; j < 8; ++j) {
      float w = wp[j];
      u16 hi = f2bf(w);
      awh[kf][j] = (short)hi;
      awl[kf][j] = (short)f2bf(w - bf2f(hi));
    }
  }

  const int bq = t >> 2, gq = t & 3;   // xp-staging role
  const int uc = t >> 6, bc = t & 63;  // gate-math role
  float c_reg = 0.f;

  for (int s = 0; s < SEQ; ++s) {
    const u16* hp = (s & 1) ? h1 : h0;
    u16* hn = (s & 1) ? h0 : h1;

    // issue xp gather early (HBM-latency hidden under MFMAs)
    const ushort4 xv =
        *(const ushort4*)(xp + ((size_t)s * 64 + bq) * G4H + gq * HIDDEN + u0);

    f32x4 acc[4] = {{0.f, 0.f, 0.f, 0.f},
                    {0.f, 0.f, 0.f, 0.f},
                    {0.f, 0.f, 0.f, 0.f},
                    {0.f, 0.f, 0.f, 0.f}};
#pragma unroll
    for (int nb = 0; nb < 4; ++nb) {
      const u16* hrow = hp + (size_t)(nb * 16 + m) * HIDDEN + kbase + kg * 8;
#pragma unroll
      for (int kf = 0; kf < 8; ++kf) {
        const bf16x8 bv = *(const bf16x8*)(hrow + kf * 32);
        acc[nb] = __builtin_amdgcn_mfma_f32_16x16x32_bf16(awh[kf], bv, acc[nb], 0, 0, 0);
        acc[nb] = __builtin_amdgcn_mfma_f32_16x16x32_bf16(awl[kf], bv, acc[nb], 0, 0, 0);
      }
    }

    xps[gq][0][bq] = bf2f(xv.x);
    xps[gq][1][bq] = bf2f(xv.y);
    xps[gq][2][bq] = bf2f(xv.z);
    xps[gq][3][bq] = bf2f(xv.w);
#pragma unroll
    for (int nb = 0; nb < 4; ++nb) {
      const int col = nb * 16 + m;
#pragma unroll
      for (int r = 0; r < 4; ++r) ps[wave][col][kg * 4 + r] = acc[nb][r];
    }
    __syncthreads();

    // gate math: thread (uc, bc)
    float g4[4];
#pragma unroll
    for (int gg = 0; gg < 4; ++gg) {
      float ssum = xps[gg][uc][bc];
#pragma unroll
      for (int w = 0; w < 4; ++w) ssum += ps[w][bc][gg * 4 + uc];
      g4[gg] = ssum;
    }
    const float ig = sigmoidf_(g4[0]);
    const float fg = sigmoidf_(g4[1]);
    const float gv = tanhf(g4[2]);
    const float og = sigmoidf_(g4[3]);
    c_reg = fg * c_reg + ig * gv;
    hn[(size_t)bc * HIDDEN + u0 + uc] = f2bf(og * tanhf(c_reg));

    __syncthreads();  // ps/xps reads done; each wave's h store drained
    if (t == 0) {
      __threadfence();  // release block's h stores to device scope
      __hip_atomic_fetch_add(cnt, 1u, __ATOMIC_RELEASE, __HIP_MEMORY_SCOPE_AGENT);
      const unsigned tgt = (unsigned)(s + 1) * NBLK;
      while (__hip_atomic_load(cnt, __ATOMIC_ACQUIRE, __HIP_MEMORY_SCOPE_AGENT) < tgt) {
        __builtin_amdgcn_s_sleep(2);
      }
    }
    __syncthreads();
    __threadfence();  // acquire: invalidate stale cached h before next read
  }
}

// =====================================================================
// h[b][k] -> hT[k][b] so phase C keeps its coalesced layout (128 KB).
// =====================================================================
__global__ __launch_bounds__(256) void transpose_h(const u16* __restrict__ h,
                                                   u16* __restrict__ hT) {
  const int e = blockIdx.x * 256 + threadIdx.x;  // e = k*64 + b
  hT[e] = h[(size_t)(e & 63) * HIDDEN + (e >> 6)];
}

// =====================================================================
// Phase C: out[b][v] = sum_k hT[k][b] * W_fc[v][k] + b_fc[v]
// =====================================================================
__global__ __launch_bounds__(256) void phaseC(
    const u16* __restrict__ hT, const float* __restrict__ Wfc,
    const float* __restrict__ bfc, float* __restrict__ out) {
  __shared__ float Ws[32][257];
  __shared__ __align__(16) u16 hs[256][64];
  const int t = threadIdx.x;
  const int v0 = blockIdx.x * 32;
  const int lane = t & 63;
  const int w = t >> 6;
  const int v = lane & 31;
  const int bbase = ((w << 1) | (lane >> 5)) << 3;
  float acc[8];
#pragma unroll
  for (int i = 0; i < 8; ++i) acc[i] = 0.f;

  for (int kc = 0; kc < HIDDEN; kc += 256) {
#pragma unroll
    for (int i = 0; i < 32; ++i) {
      int e = t + i * 256;
      int vv = e >> 8, k = e & 255;
      Ws[vv][k] = Wfc[((size_t)(v0 + vv)) * HIDDEN + kc + k];
    }
#pragma unroll
    for (int i = 0; i < 16; ++i) {
      int e = t + i * 256;
      int k = e >> 4, b4 = e & 15;
      *(ushort4*)&hs[k][b4 * 4] =
          *(const ushort4*)&hT[(size_t)(kc + k) * 64 + b4 * 4];
    }
    __syncthreads();
    for (int k = 0; k < 256; ++k) {
      const float wv = Ws[v][k];
      const uint4 h4 = *(const uint4*)&hs[k][bbase];
      acc[0] = fmaf(wv, __uint_as_float(h4.x << 16), acc[0]);
      acc[1] = fmaf(wv, __uint_as_float(h4.x & 0xffff0000u), acc[1]);
      acc[2] = fmaf(wv, __uint_as_float(h4.y << 16), acc[2]);
      acc[3] = fmaf(wv, __uint_as_float(h4.y & 0xffff0000u), acc[3]);
      acc[4] = fmaf(wv, __uint_as_float(h4.z << 16), acc[4]);
      acc[5] = fmaf(wv, __uint_as_float(h4.z & 0xffff0000u), acc[5]);
      acc[6] = fmaf(wv, __uint_as_float(h4.w << 16), acc[6]);
      acc[7] = fmaf(wv, __uint_as_float(h4.w & 0xffff0000u), acc[7]);
    }
    __syncthreads();
  }
  const float bias = bfc[v0 + v];
#pragma unroll
  for (int i = 0; i < 8; ++i) {
    out[(size_t)(bbase + i) * VOCAB + v0 + v] = acc[i] + bias;
  }
}

// =====================================================================
extern "C" void kernel_launch(void* const* d_in, const int* in_sizes, int n_in,
                              void* d_out, int out_size, void* d_ws,
                              size_t ws_size, hipStream_t stream) {
  const int* x = (const int*)d_in[0];
  const float* emb = (const float*)d_in[1];
  const float* Wih = (const float*)d_in[2];
  const float* Whh = (const float*)d_in[3];
  const float* bih = (const float*)d_in[4];
  const float* bhh = (const float*)d_in[5];
  const float* Wfc = (const float*)d_in[6];
  const float* bfc = (const float*)d_in[7];
  float* out = (float*)d_out;

  char* ws = (char*)d_ws;
  const size_t XP_BYTES = (size_t)BATCH * SEQ * G4H * sizeof(u16);  // 256 MB
  const size_t HB = (size_t)BATCH * HIDDEN * sizeof(u16);           // 128 KB
  u16* xp = (u16*)ws;
  u16* hA = (u16*)(ws + XP_BYTES);
  u16* hB = (u16*)(ws + XP_BYTES + HB);
  u16* hT = (u16*)(ws + XP_BYTES + 2 * HB);
  unsigned* cnt = (unsigned*)(ws + XP_BYTES + 3 * HB);

  hipMemsetAsync(hA, 0, HB, stream);
  hipMemsetAsync(cnt, 0, sizeof(unsigned), stream);

  phaseA<<<dim3(64, 512), 256, 0, stream>>>(x, emb, Wih, bih, bhh, xp);

  {
    const u16* xp_c = xp;
    const float* Whh_c = Whh;
    void* args[] = {(void*)&xp_c, (void*)&Whh_c, (void*)&hA, (void*)&hB,
                    (void*)&cnt};
    hipLaunchCooperativeKernel((const void*)lstm_steps, dim3(NBLK), dim3(256),
                               args, 0, stream);
  }

  // SEQ even -> final h in hA
  transpose_h<<<(BATCH * HIDDEN) / 256, 256, 0, stream>>>(hA, hT);
  phaseC<<<1000, 256, 0, stream>>>(hT, Wfc, bfc, out);
}

// Round 3
// 16263.237 us; speedup vs baseline: 1.7129x; 1.7129x over previous
//
#include <hip/hip_runtime.h>

typedef unsigned short u16;
typedef float f32x4 __attribute__((ext_vector_type(4)));
typedef _Float16 f16x8 __attribute__((ext_vector_type(8)));

#define VOCAB 32000
#define EMBED 512
#define HIDDEN 1024
#define BATCH 64
#define SEQ 512
#define G4H 4096
#define LBLK 64  // lstm persistent blocks

// ---------- fp16 helpers ----------
static __device__ __forceinline__ float h2f(u16 v) {
  _Float16 h;
  __builtin_memcpy(&h, &v, 2);
  return (float)h;
}
static __device__ __forceinline__ u16 f2h(float f) {
  _Float16 h = (_Float16)f;
  u16 v;
  __builtin_memcpy(&v, &h, 2);
  return v;
}
static __device__ __forceinline__ float sigmoidf_(float x) {
  return 1.f / (1.f + __expf(-x));
}

// =====================================================================
// Phase A: xp = emb_table[x] @ W_ih^T + b_ih + b_hh, fp16 MFMA GEMM.
// M=32768 (m = b*512+t), K=512, N=4096. Output layout [t][b][u][c]
// (gate-interleaved: column position = u*4 + c). A tile's 128 N-columns
// cover u in [bx*32, bx*32+32) x c in [0,4): nloc = uu*4+c, weight row
// = u0 + (nloc>>2) + (nloc&3)*1024. 128x128 tile, BK=32, 4 waves,
// reg-staged f32->fp16 conversion into LDS.
// MFMA 16x16x32 f16: A lane l -> A[m=l&15][k=(l>>4)*8+j]; D: col=l&15,
// row=(l>>4)*4+r.
// =====================================================================
__global__ __launch_bounds__(256, 2) void phaseA(
    const int* __restrict__ x, const float* __restrict__ emb,
    const float* __restrict__ Wih, const float* __restrict__ bih,
    const float* __restrict__ bhh, u16* __restrict__ xp) {
  __shared__ __align__(16) _Float16 Al[128 * 32];
  __shared__ __align__(16) _Float16 Bl[128 * 32];
  const int t = threadIdx.x;
  const int bx = blockIdx.x;  // n-tile 0..31
  const int by = blockIdx.y;  // m-tile 0..255
  const int m0 = by * 128;
  const int u0 = bx * 32;

  // staging roles: chunk e in {t, t+256}; row = e>>2, kq = e&3 (8 fp16 each)
  const int r0 = x[m0 + (t >> 2)];
  const int r1 = x[m0 + 64 + (t >> 2)];
  const int nl0 = t >> 2, nl1 = 64 + (t >> 2);
  const int wrow0 = u0 + (nl0 >> 2) + (nl0 & 3) * 1024;
  const int wrow1 = u0 + (nl1 >> 2) + (nl1 & 3) * 1024;
  const int kq = t & 3;

  const int wid = t >> 6, l = t & 63;
  const int wr = wid >> 1, wc = wid & 1;  // wave quadrant (2x2 of 64x64)
  const int lm = l & 15, lk = l >> 4;

  f32x4 acc[4][4];
#pragma unroll
  for (int i = 0; i < 4; ++i)
#pragma unroll
    for (int j = 0; j < 4; ++j) acc[i][j] = (f32x4){0.f, 0.f, 0.f, 0.f};

  for (int k0 = 0; k0 < EMBED; k0 += 32) {
    {
      const float* sa0 = emb + (size_t)r0 * EMBED + k0 + kq * 8;
      const float* sa1 = emb + (size_t)r1 * EMBED + k0 + kq * 8;
      const float* sb0 = Wih + (size_t)wrow0 * EMBED + k0 + kq * 8;
      const float* sb1 = Wih + (size_t)wrow1 * EMBED + k0 + kq * 8;
      float4 a00 = *(const float4*)sa0, a01 = *(const float4*)(sa0 + 4);
      float4 a10 = *(const float4*)sa1, a11 = *(const float4*)(sa1 + 4);
      float4 b00 = *(const float4*)sb0, b01 = *(const float4*)(sb0 + 4);
      float4 b10 = *(const float4*)sb1, b11 = *(const float4*)(sb1 + 4);
      f16x8 va0, va1, vb0, vb1;
      va0[0] = (_Float16)a00.x; va0[1] = (_Float16)a00.y;
      va0[2] = (_Float16)a00.z; va0[3] = (_Float16)a00.w;
      va0[4] = (_Float16)a01.x; va0[5] = (_Float16)a01.y;
      va0[6] = (_Float16)a01.z; va0[7] = (_Float16)a01.w;
      va1[0] = (_Float16)a10.x; va1[1] = (_Float16)a10.y;
      va1[2] = (_Float16)a10.z; va1[3] = (_Float16)a10.w;
      va1[4] = (_Float16)a11.x; va1[5] = (_Float16)a11.y;
      va1[6] = (_Float16)a11.z; va1[7] = (_Float16)a11.w;
      vb0[0] = (_Float16)b00.x; vb0[1] = (_Float16)b00.y;
      vb0[2] = (_Float16)b00.z; vb0[3] = (_Float16)b00.w;
      vb0[4] = (_Float16)b01.x; vb0[5] = (_Float16)b01.y;
      vb0[6] = (_Float16)b01.z; vb0[7] = (_Float16)b01.w;
      vb1[0] = (_Float16)b10.x; vb1[1] = (_Float16)b10.y;
      vb1[2] = (_Float16)b10.z; vb1[3] = (_Float16)b10.w;
      vb1[4] = (_Float16)b11.x; vb1[5] = (_Float16)b11.y;
      vb1[6] = (_Float16)b11.z; vb1[7] = (_Float16)b11.w;
      *(f16x8*)(Al + t * 8) = va0;
      *(f16x8*)(Al + (t + 256) * 8) = va1;
      *(f16x8*)(Bl + t * 8) = vb0;
      *(f16x8*)(Bl + (t + 256) * 8) = vb1;
    }
    __syncthreads();
    f16x8 af[4], bf[4];
#pragma unroll
    for (int mt = 0; mt < 4; ++mt)
      af[mt] = *(const f16x8*)(Al + (wr * 64 + mt * 16 + lm) * 32 + lk * 8);
#pragma unroll
    for (int nt = 0; nt < 4; ++nt)
      bf[nt] = *(const f16x8*)(Bl + (wc * 64 + nt * 16 + lm) * 32 + lk * 8);
#pragma unroll
    for (int mt = 0; mt < 4; ++mt)
#pragma unroll
      for (int nt = 0; nt < 4; ++nt)
        acc[mt][nt] = __builtin_amdgcn_mfma_f32_16x16x32_f16(
            af[mt], bf[nt], acc[mt][nt], 0, 0, 0);
    __syncthreads();
  }

#pragma unroll
  for (int nt = 0; nt < 4; ++nt) {
    const int nloc = wc * 64 + nt * 16 + lm;
    const int grow = u0 + (nloc >> 2) + (nloc & 3) * 1024;
    const float bsum = bih[grow] + bhh[grow];
#pragma unroll
    for (int mt = 0; mt < 4; ++mt)
#pragma unroll
      for (int r = 0; r < 4; ++r) {
        const int m = m0 + wr * 64 + mt * 16 + lk * 4 + r;
        const int bb = m >> 9, tt = m & 511;
        xp[((size_t)tt * 64 + bb) * G4H + bx * 128 + nloc] =
            f2h(acc[mt][nt][r] + bsum);
      }
  }
}

// =====================================================================
// Persistent LSTM, 64 blocks x 1024 thr (16 waves), cooperative.
// Block owns units [blk*16, blk*16+16) x 4 gates. Wave (c, kw): gate c,
// K-quarter kw. W_hh rows in VGPRs as fp16 A-frags for all 512 steps.
// h (fp16, [b][k]) double-buffered in global, read by all blocks from
// L2/L3. Partial K-sums reduced via padded LDS. c in registers.
// Grid sync: distributed per-block flags (own cacheline each) +
// one-wave parallel poll; release = threadfence+flag store, acquire =
// poll + threadfence (buffer_inv). O(1) contention vs R2's O(n) counter.
// =====================================================================
__global__ __launch_bounds__(1024, 4) void lstm_steps(
    const u16* __restrict__ xp, const float* __restrict__ Whh,
    _Float16* __restrict__ hA, _Float16* __restrict__ hB,
    unsigned* __restrict__ flags) {
  __shared__ float ps[16 * 16 * 65];  // [kw*4+c][row 16][65-padded cols]
  const int t = threadIdx.x;
  const int blk = blockIdx.x;
  const int wid = t >> 6, l = t & 63;
  const int c = wid >> 2, kw = wid & 3;
  const int lm = l & 15, lk = l >> 4;

  // ---- W_hh A-frags (fp16), once ----
  f16x8 wf[8];
  {
    const float* wp = Whh + (size_t)(c * HIDDEN + blk * 16 + lm) * HIDDEN +
                      kw * 256 + lk * 8;
#pragma unroll
    for (int ks = 0; ks < 8; ++ks) {
      float4 w0 = *(const float4*)(wp + ks * 32);
      float4 w1 = *(const float4*)(wp + ks * 32 + 4);
      f16x8 v;
      v[0] = (_Float16)w0.x; v[1] = (_Float16)w0.y;
      v[2] = (_Float16)w0.z; v[3] = (_Float16)w0.w;
      v[4] = (_Float16)w1.x; v[5] = (_Float16)w1.y;
      v[6] = (_Float16)w1.z; v[7] = (_Float16)w1.w;
      wf[ks] = v;
    }
  }

  const int gb = t >> 4, gu = t & 15;  // gate-math role: batch, unit
  const size_t xpofs = (size_t)gb * G4H + (size_t)(blk * 16 + gu) * 4;
  float c_reg = 0.f;

  for (int s = 0; s < SEQ; ++s) {
    const _Float16* hp = (s & 1) ? hB : hA;
    _Float16* hn = (s & 1) ? hA : hB;

    // xp gather early (8B per thread, coalesced; hides under MFMAs)
    const ushort4 xv = *(const ushort4*)(xp + (size_t)s * 64 * G4H + xpofs);

    f32x4 acc[4] = {{0.f, 0.f, 0.f, 0.f},
                    {0.f, 0.f, 0.f, 0.f},
                    {0.f, 0.f, 0.f, 0.f},
                    {0.f, 0.f, 0.f, 0.f}};
#pragma unroll
    for (int ks = 0; ks < 8; ++ks) {
#pragma unroll
      for (int bt = 0; bt < 4; ++bt) {
        const f16x8 bv = *(const f16x8*)(hp + (size_t)(bt * 16 + lm) * HIDDEN +
                                         kw * 256 + ks * 32 + lk * 8);
        acc[bt] =
            __builtin_amdgcn_mfma_f32_16x16x32_f16(wf[ks], bv, acc[bt], 0, 0, 0);
      }
    }
#pragma unroll
    for (int bt = 0; bt < 4; ++bt)
#pragma unroll
      for (int r = 0; r < 4; ++r)
        ps[((kw * 4 + c) * 16 + lk * 4 + r) * 65 + bt * 16 + lm] = acc[bt][r];
    __syncthreads();

    // gate math: thread (gb, gu)
    float g4[4];
#pragma unroll
    for (int cc = 0; cc < 4; ++cc) {
      float ssum = 0.f;
#pragma unroll
      for (int kk = 0; kk < 4; ++kk)
        ssum += ps[((kk * 4 + cc) * 16 + gu) * 65 + gb];
      g4[cc] = ssum;
    }
    g4[0] += h2f(xv.x);
    g4[1] += h2f(xv.y);
    g4[2] += h2f(xv.z);
    g4[3] += h2f(xv.w);
    const float ig = sigmoidf_(g4[0]);
    const float fg = sigmoidf_(g4[1]);
    const float gg = tanhf(g4[2]);
    const float og = sigmoidf_(g4[3]);
    c_reg = fg * c_reg + ig * gg;
    hn[(size_t)gb * HIDDEN + blk * 16 + gu] = (_Float16)(og * tanhf(c_reg));

    if (s == SEQ - 1) break;  // last h consumed by next dispatch

    __syncthreads();  // all waves' h stores complete (vmcnt0 before barrier)
    if (t == 0) {
      __threadfence();  // release: write back L2 so other XCDs can see h
      __hip_atomic_store(flags + blk * 32, (unsigned)(s + 1), __ATOMIC_RELAXED,
                         __HIP_MEMORY_SCOPE_AGENT);
    }
    if (t < LBLK) {  // one wave polls all 64 flags in parallel
      const unsigned tgt = (unsigned)(s + 1);
      while (true) {
        unsigned v = __hip_atomic_load(flags + t * 32, __ATOMIC_RELAXED,
                                       __HIP_MEMORY_SCOPE_AGENT);
        if (__all((int)(v >= tgt))) break;
        __builtin_amdgcn_s_sleep(1);
      }
    }
    __syncthreads();
    __threadfence();  // acquire: invalidate stale h before next step's reads
  }
}

// =====================================================================
// h[b][k] -> hT[k][b] (raw u16 copy; fp16 bits)
// =====================================================================
__global__ __launch_bounds__(256) void transpose_h(const u16* __restrict__ h,
                                                   u16* __restrict__ hT) {
  const int e = blockIdx.x * 256 + threadIdx.x;  // e = k*64 + b
  hT[e] = h[(size_t)(e & 63) * HIDDEN + (e >> 6)];
}

// =====================================================================
// Phase C: out[b][v] = sum_k hT[k][b] * W_fc[v][k] + b_fc[v]
// 1000 blocks x 256 thr; kc=128 chunks; h converted fp16->f32 at staging.
// =====================================================================
__global__ __launch_bounds__(256) void phaseC(
    const u16* __restrict__ hT, const float* __restrict__ Wfc,
    const float* __restrict__ bfc, float* __restrict__ out) {
  __shared__ float Ws[32][129];
  __shared__ __align__(16) float hs[128][68];
  const int t = threadIdx.x;
  const int v0 = blockIdx.x * 32;
  const int lane = t & 63;
  const int w = t >> 6;
  const int v = lane & 31;
  const int bbase = ((w << 1) | (lane >> 5)) << 3;
  float acc[8] = {0.f, 0.f, 0.f, 0.f, 0.f, 0.f, 0.f, 0.f};

  for (int kc = 0; kc < HIDDEN; kc += 128) {
#pragma unroll
    for (int i = 0; i < 16; ++i) {
      int e = t + i * 256;
      Ws[e >> 7][e & 127] =
          Wfc[(size_t)(v0 + (e >> 7)) * HIDDEN + kc + (e & 127)];
    }
#pragma unroll
    for (int i = 0; i < 8; ++i) {
      int e = t + i * 256;
      int k = e >> 4, b4 = e & 15;
      ushort4 hv = *(const ushort4*)&hT[(size_t)(kc + k) * 64 + b4 * 4];
      float4 fv = {h2f(hv.x), h2f(hv.y), h2f(hv.z), h2f(hv.w)};
      *(float4*)&hs[k][b4 * 4] = fv;
    }
    __syncthreads();
    for (int k = 0; k < 128; ++k) {
      const float wv = Ws[v][k];
      const float4 ha = *(const float4*)&hs[k][bbase];
      const float4 hb = *(const float4*)&hs[k][bbase + 4];
      acc[0] = fmaf(wv, ha.x, acc[0]);
      acc[1] = fmaf(wv, ha.y, acc[1]);
      acc[2] = fmaf(wv, ha.z, acc[2]);
      acc[3] = fmaf(wv, ha.w, acc[3]);
      acc[4] = fmaf(wv, hb.x, acc[4]);
      acc[5] = fmaf(wv, hb.y, acc[5]);
      acc[6] = fmaf(wv, hb.z, acc[6]);
      acc[7] = fmaf(wv, hb.w, acc[7]);
    }
    __syncthreads();
  }
  const float bias = bfc[v0 + v];
#pragma unroll
  for (int i = 0; i < 8; ++i)
    out[(size_t)(bbase + i) * VOCAB + v0 + v] = acc[i] + bias;
}

// =====================================================================
extern "C" void kernel_launch(void* const* d_in, const int* in_sizes, int n_in,
                              void* d_out, int out_size, void* d_ws,
                              size_t ws_size, hipStream_t stream) {
  const int* x = (const int*)d_in[0];
  const float* emb = (const float*)d_in[1];
  const float* Wih = (const float*)d_in[2];
  const float* Whh = (const float*)d_in[3];
  const float* bih = (const float*)d_in[4];
  const float* bhh = (const float*)d_in[5];
  const float* Wfc = (const float*)d_in[6];
  const float* bfc = (const float*)d_in[7];
  float* out = (float*)d_out;

  char* ws = (char*)d_ws;
  const size_t XPB = (size_t)SEQ * 64 * G4H * sizeof(u16);  // 256 MiB
  u16* xp = (u16*)ws;
  _Float16* hA = (_Float16*)(ws + XPB);
  _Float16* hB = (_Float16*)(ws + XPB + 131072);
  u16* hT = (u16*)(ws + XPB + 262144);
  unsigned* flags = (unsigned*)(ws + XPB + 393216);  // 64 x 128B

  hipMemsetAsync(hA, 0, 131072, stream);
  hipMemsetAsync(flags, 0, LBLK * 128, stream);

  phaseA<<<dim3(32, 256), 256, 0, stream>>>(x, emb, Wih, bih, bhh, xp);

  {
    const u16* xp_c = xp;
    const float* Whh_c = Whh;
    void* args[] = {(void*)&xp_c, (void*)&Whh_c, (void*)&hA, (void*)&hB,
                    (void*)&flags};
    hipLaunchCooperativeKernel((const void*)lstm_steps, dim3(LBLK), dim3(1024),
                               args, 0, stream);
  }

  // SEQ even -> final h written at s=511 (odd) into hA
  transpose_h<<<256, 256, 0, stream>>>((const u16*)hA, hT);
  phaseC<<<1000, 256, 0, stream>>>(hT, Wfc, bfc, out);
}

// Round 4
// 4248.261 us; speedup vs baseline: 6.5575x; 3.8282x over previous
//
#include <hip/hip_runtime.h>

typedef unsigned short u16;
typedef float f32x4 __attribute__((ext_vector_type(4)));
typedef _Float16 f16x8 __attribute__((ext_vector_type(8)));

#define VOCAB 32000
#define EMBED 512
#define HIDDEN 1024
#define BATCH 64
#define SEQ 512
#define G4H 4096
#define LBLK 64  // lstm persistent blocks

// ---------- fp16 helpers ----------
static __device__ __forceinline__ float h2f(u16 v) {
  _Float16 h;
  __builtin_memcpy(&h, &v, 2);
  return (float)h;
}
static __device__ __forceinline__ u16 f2h(float f) {
  _Float16 h = (_Float16)f;
  u16 v;
  __builtin_memcpy(&v, &h, 2);
  return v;
}
static __device__ __forceinline__ float sigmoidf_(float x) {
  return 1.f / (1.f + __expf(-x));
}
static __device__ __forceinline__ f16x8 cvt8(const float* p) {
  float4 a = *(const float4*)p, b = *(const float4*)(p + 4);
  f16x8 v;
  v[0] = (_Float16)a.x; v[1] = (_Float16)a.y;
  v[2] = (_Float16)a.z; v[3] = (_Float16)a.w;
  v[4] = (_Float16)b.x; v[5] = (_Float16)b.y;
  v[6] = (_Float16)b.z; v[7] = (_Float16)b.w;
  return v;
}

// coherent (cross-XCD) 16B load: bypasses L1/L2, served by IF/L3
#define GLOADC(dst, addr)                                  \
  asm volatile("global_load_dwordx4 %0, %1, off sc0 sc1"  \
               : "=v"(dst)                                 \
               : "v"(addr)                                 \
               : "memory")

// =====================================================================
// Phase A: xp = emb_table[x] @ W_ih^T + b_ih + b_hh, fp16 MFMA GEMM.
// Output layout [t][b][u*4+c]. (unchanged from R3 — verified)
// =====================================================================
__global__ __launch_bounds__(256, 2) void phaseA(
    const int* __restrict__ x, const float* __restrict__ emb,
    const float* __restrict__ Wih, const float* __restrict__ bih,
    const float* __restrict__ bhh, u16* __restrict__ xp) {
  __shared__ __align__(16) _Float16 Al[128 * 32];
  __shared__ __align__(16) _Float16 Bl[128 * 32];
  const int t = threadIdx.x;
  const int bx = blockIdx.x;  // n-tile 0..31
  const int by = blockIdx.y;  // m-tile 0..255
  const int m0 = by * 128;
  const int u0 = bx * 32;

  const int r0 = x[m0 + (t >> 2)];
  const int r1 = x[m0 + 64 + (t >> 2)];
  const int nl0 = t >> 2, nl1 = 64 + (t >> 2);
  const int wrow0 = u0 + (nl0 >> 2) + (nl0 & 3) * 1024;
  const int wrow1 = u0 + (nl1 >> 2) + (nl1 & 3) * 1024;
  const int kq = t & 3;

  const int wid = t >> 6, l = t & 63;
  const int wr = wid >> 1, wc = wid & 1;
  const int lm = l & 15, lk = l >> 4;

  f32x4 acc[4][4];
#pragma unroll
  for (int i = 0; i < 4; ++i)
#pragma unroll
    for (int j = 0; j < 4; ++j) acc[i][j] = (f32x4){0.f, 0.f, 0.f, 0.f};

  for (int k0 = 0; k0 < EMBED; k0 += 32) {
    *(f16x8*)(Al + t * 8) = cvt8(emb + (size_t)r0 * EMBED + k0 + kq * 8);
    *(f16x8*)(Al + (t + 256) * 8) = cvt8(emb + (size_t)r1 * EMBED + k0 + kq * 8);
    *(f16x8*)(Bl + t * 8) = cvt8(Wih + (size_t)wrow0 * EMBED + k0 + kq * 8);
    *(f16x8*)(Bl + (t + 256) * 8) = cvt8(Wih + (size_t)wrow1 * EMBED + k0 + kq * 8);
    __syncthreads();
    f16x8 af[4], bf[4];
#pragma unroll
    for (int mt = 0; mt < 4; ++mt)
      af[mt] = *(const f16x8*)(Al + (wr * 64 + mt * 16 + lm) * 32 + lk * 8);
#pragma unroll
    for (int nt = 0; nt < 4; ++nt)
      bf[nt] = *(const f16x8*)(Bl + (wc * 64 + nt * 16 + lm) * 32 + lk * 8);
#pragma unroll
    for (int mt = 0; mt < 4; ++mt)
#pragma unroll
      for (int nt = 0; nt < 4; ++nt)
        acc[mt][nt] = __builtin_amdgcn_mfma_f32_16x16x32_f16(
            af[mt], bf[nt], acc[mt][nt], 0, 0, 0);
    __syncthreads();
  }

#pragma unroll
  for (int nt = 0; nt < 4; ++nt) {
    const int nloc = wc * 64 + nt * 16 + lm;
    const int grow = u0 + (nloc >> 2) + (nloc & 3) * 1024;
    const float bsum = bih[grow] + bhh[grow];
#pragma unroll
    for (int mt = 0; mt < 4; ++mt)
#pragma unroll
      for (int r = 0; r < 4; ++r) {
        const int m = m0 + wr * 64 + mt * 16 + lk * 4 + r;
        const int bb = m >> 9, tt = m & 511;
        xp[((size_t)tt * 64 + bb) * G4H + bx * 128 + nloc] =
            f2h(acc[mt][nt][r] + bsum);
      }
  }
}

// =====================================================================
// Persistent LSTM, 64 blocks x 512 thr (8 waves), cooperative.
// Block owns 16 units x 4 gates (64 Whh rows). Wave kw owns K-slice
// [kw*128, kw*128+128) for ALL 64 rows -> every h element read exactly
// once per block (no redundancy). h exchange via per-access coherent
// (sc0 sc1) loads/stores -- NO L2 wbl2/inv fences. bt-pipelined loads
// with counted vmcnt. kw-reduction via fp16 LDS ps[row][b][kw8],
// XOR-swizzled. c in registers. Flag barrier, relaxed atomics.
// =====================================================================
__global__ __launch_bounds__(512, 2) void lstm_steps(
    const u16* __restrict__ xp, const float* __restrict__ Whh,
    u16* __restrict__ hA, u16* __restrict__ hB, unsigned* __restrict__ flags) {
  __shared__ __align__(16) u16 ps[64 * 64 * 8];  // [row][b][kw], swizzled
  char* psb = (char*)ps;
  const int t = threadIdx.x;
  const int blk = blockIdx.x;
  const int kw = t >> 6;  // wave id = K-slice
  const int l = t & 63;
  const int lm = l & 15, lk = l >> 4;

  // ---- W_hh A-frags (fp16), once: wf[rt=gate][kf] ----
  f16x8 wf[4][4];
#pragma unroll
  for (int rt = 0; rt < 4; ++rt)
#pragma unroll
    for (int kf = 0; kf < 4; ++kf)
      wf[rt][kf] = cvt8(Whh + (size_t)(rt * HIDDEN + blk * 16 + lm) * HIDDEN +
                        kw * 128 + kf * 32 + lk * 8);

  const int gb = t >> 3, gup = t & 7;  // gate-math role: batch, unit-pair
  float c0 = 0.f, c1 = 0.f;

  for (int s = 0; s < SEQ; ++s) {
    const u16* hp = (s & 1) ? hB : hA;
    u16* hn = (s & 1) ? hA : hB;

    // xp slice for gate math (issued first; retires with first wait)
    f16x8 xv;
    GLOADC(xv, xp + (size_t)s * (64 * G4H) + (size_t)gb * G4H + blk * 64 + gup * 8);

    // prefetch bt=0 h fragments
    f16x8 bv[2][4];
#pragma unroll
    for (int kf = 0; kf < 4; ++kf)
      GLOADC(bv[0][kf], hp + (size_t)lm * HIDDEN + kw * 128 + kf * 32 + lk * 8);

    f32x4 acc[4][4];
#pragma unroll
    for (int i = 0; i < 4; ++i)
#pragma unroll
      for (int j = 0; j < 4; ++j) acc[i][j] = (f32x4){0.f, 0.f, 0.f, 0.f};

#pragma unroll
    for (int bt = 0; bt < 4; ++bt) {
      const int cur = bt & 1;
      if (bt < 3) {
        const int nxt = cur ^ 1;
#pragma unroll
        for (int kf = 0; kf < 4; ++kf)
          GLOADC(bv[nxt][kf], hp + (size_t)((bt + 1) * 16 + lm) * HIDDEN +
                                  kw * 128 + kf * 32 + lk * 8);
        asm volatile("s_waitcnt vmcnt(4)" ::: "memory");
      } else {
        asm volatile("s_waitcnt vmcnt(0)" ::: "memory");
      }
      __builtin_amdgcn_sched_barrier(0);
#pragma unroll
      for (int rt = 0; rt < 4; ++rt)
#pragma unroll
        for (int kf = 0; kf < 4; ++kf)
          acc[rt][bt] = __builtin_amdgcn_mfma_f32_16x16x32_f16(
              wf[rt][kf], bv[cur][kf], acc[rt][bt], 0, 0, 0);
    }

    // ps[row][b][kw] fp16, byte ^= ((row&7)<<4)
#pragma unroll
    for (int rt = 0; rt < 4; ++rt)
#pragma unroll
      for (int bt = 0; bt < 4; ++bt)
#pragma unroll
        for (int r = 0; r < 4; ++r) {
          const int row = rt * 16 + lk * 4 + r;
          const int bb = bt * 16 + lm;
          const unsigned off =
              (unsigned)(row * 1024 + bb * 16 + kw * 2) ^
              (unsigned)((row & 7) << 4);
          *(u16*)(psb + off) = f2h(acc[rt][bt][r]);
        }
    __syncthreads();

    // ---- gate math: thread (gb, gup) -> units gup*2, gup*2+1 ----
    float go0, go1;
    {
      const int u0 = gup * 2;
      float gg0[4], gg1[4];
#pragma unroll
      for (int c = 0; c < 4; ++c) {
        const int row0 = c * 16 + u0;
        const unsigned o0 = (unsigned)(row0 * 1024 + gb * 16) ^
                            (unsigned)((row0 & 7) << 4);
        const f16x8 p0 = *(const f16x8*)(psb + o0);
        const int row1 = row0 + 1;
        const unsigned o1 = (unsigned)(row1 * 1024 + gb * 16) ^
                            (unsigned)((row1 & 7) << 4);
        const f16x8 p1 = *(const f16x8*)(psb + o1);
        gg0[c] = ((float)p0[0] + (float)p0[1]) + ((float)p0[2] + (float)p0[3]) +
                 ((float)p0[4] + (float)p0[5]) + ((float)p0[6] + (float)p0[7]) +
                 (float)xv[c];
        gg1[c] = ((float)p1[0] + (float)p1[1]) + ((float)p1[2] + (float)p1[3]) +
                 ((float)p1[4] + (float)p1[5]) + ((float)p1[6] + (float)p1[7]) +
                 (float)xv[4 + c];
      }
      {
        const float ig = sigmoidf_(gg0[0]), fg = sigmoidf_(gg0[1]);
        const float gv = tanhf(gg0[2]), og = sigmoidf_(gg0[3]);
        c0 = fg * c0 + ig * gv;
        go0 = og * tanhf(c0);
      }
      {
        const float ig = sigmoidf_(gg1[0]), fg = sigmoidf_(gg1[1]);
        const float gv = tanhf(gg1[2]), og = sigmoidf_(gg1[3]);
        c1 = fg * c1 + ig * gv;
        go1 = og * tanhf(c1);
      }
    }
    const unsigned hpack = (unsigned)f2h(go0) | ((unsigned)f2h(go1) << 16);
    __hip_atomic_store(
        (unsigned*)(hn + (size_t)gb * HIDDEN + blk * 16 + gup * 2), hpack,
        __ATOMIC_RELAXED, __HIP_MEMORY_SCOPE_AGENT);

    if (s == SEQ - 1) break;

    // drain own h store (write-through ack) before signaling
    asm volatile("s_waitcnt vmcnt(0)" ::: "memory");
    __syncthreads();  // all waves' h stores drained; ps reads done
    if (t == 0)
      __hip_atomic_store(flags + blk * 32, (unsigned)(s + 1), __ATOMIC_RELAXED,
                         __HIP_MEMORY_SCOPE_AGENT);
    if (t < LBLK) {
      const unsigned tgt = (unsigned)(s + 1);
      while (true) {
        unsigned v = __hip_atomic_load(flags + t * 32, __ATOMIC_RELAXED,
                                       __HIP_MEMORY_SCOPE_AGENT);
        if (__all((int)(v >= tgt))) break;
        __builtin_amdgcn_s_sleep(1);
      }
    }
    __syncthreads();
  }
}

// =====================================================================
// h[b][k] -> hT[k][b] (raw u16 copy; fp16 bits)
// =====================================================================
__global__ __launch_bounds__(256) void transpose_h(const u16* __restrict__ h,
                                                   u16* __restrict__ hT) {
  const int e = blockIdx.x * 256 + threadIdx.x;  // e = k*64 + b
  hT[e] = h[(size_t)(e & 63) * HIDDEN + (e >> 6)];
}

// =====================================================================
// Phase C: out[b][v] = sum_k hT[k][b] * W_fc[v][k] + b_fc[v]
// =====================================================================
__global__ __launch_bounds__(256) void phaseC(
    const u16* __restrict__ hT, const float* __restrict__ Wfc,
    const float* __restrict__ bfc, float* __restrict__ out) {
  __shared__ float Ws[32][129];
  __shared__ __align__(16) float hs[128][68];
  const int t = threadIdx.x;
  const int v0 = blockIdx.x * 32;
  const int lane = t & 63;
  const int w = t >> 6;
  const int v = lane & 31;
  const int bbase = ((w << 1) | (lane >> 5)) << 3;
  float acc[8] = {0.f, 0.f, 0.f, 0.f, 0.f, 0.f, 0.f, 0.f};

  for (int kc = 0; kc < HIDDEN; kc += 128) {
#pragma unroll
    for (int i = 0; i < 16; ++i) {
      int e = t + i * 256;
      Ws[e >> 7][e & 127] =
          Wfc[(size_t)(v0 + (e >> 7)) * HIDDEN + kc + (e & 127)];
    }
#pragma unroll
    for (int i = 0; i < 8; ++i) {
      int e = t + i * 256;
      int k = e >> 4, b4 = e & 15;
      ushort4 hv = *(const ushort4*)&hT[(size_t)(kc + k) * 64 + b4 * 4];
      float4 fv = {h2f(hv.x), h2f(hv.y), h2f(hv.z), h2f(hv.w)};
      *(float4*)&hs[k][b4 * 4] = fv;
    }
    __syncthreads();
    for (int k = 0; k < 128; ++k) {
      const float wv = Ws[v][k];
      const float4 ha = *(const float4*)&hs[k][bbase];
      const float4 hb = *(const float4*)&hs[k][bbase + 4];
      acc[0] = fmaf(wv, ha.x, acc[0]);
      acc[1] = fmaf(wv, ha.y, acc[1]);
      acc[2] = fmaf(wv, ha.z, acc[2]);
      acc[3] = fmaf(wv, ha.w, acc[3]);
      acc[4] = fmaf(wv, hb.x, acc[4]);
      acc[5] = fmaf(wv, hb.y, acc[5]);
      acc[6] = fmaf(wv, hb.z, acc[6]);
      acc[7] = fmaf(wv, hb.w, acc[7]);
    }
    __syncthreads();
  }
  const float bias = bfc[v0 + v];
#pragma unroll
  for (int i = 0; i < 8; ++i)
    out[(size_t)(bbase + i) * VOCAB + v0 + v] = acc[i] + bias;
}

// =====================================================================
extern "C" void kernel_launch(void* const* d_in, const int* in_sizes, int n_in,
                              void* d_out, int out_size, void* d_ws,
                              size_t ws_size, hipStream_t stream) {
  const int* x = (const int*)d_in[0];
  const float* emb = (const float*)d_in[1];
  const float* Wih = (const float*)d_in[2];
  const float* Whh = (const float*)d_in[3];
  const float* bih = (const float*)d_in[4];
  const float* bhh = (const float*)d_in[5];
  const float* Wfc = (const float*)d_in[6];
  const float* bfc = (const float*)d_in[7];
  float* out = (float*)d_out;

  char* ws = (char*)d_ws;
  const size_t XPB = (size_t)SEQ * 64 * G4H * sizeof(u16);  // 256 MiB
  u16* xp = (u16*)ws;
  u16* hA = (u16*)(ws + XPB);
  u16* hB = (u16*)(ws + XPB + 131072);
  u16* hT = (u16*)(ws + XPB + 262144);
  unsigned* flags = (unsigned*)(ws + XPB + 393216);  // 64 x 128B

  hipMemsetAsync(hA, 0, 131072, stream);
  hipMemsetAsync(flags, 0, LBLK * 128, stream);

  phaseA<<<dim3(32, 256), 256, 0, stream>>>(x, emb, Wih, bih, bhh, xp);

  {
    const u16* xp_c = xp;
    const float* Whh_c = Whh;
    void* args[] = {(void*)&xp_c, (void*)&Whh_c, (void*)&hA, (void*)&hB,
                    (void*)&flags};
    hipLaunchCooperativeKernel((const void*)lstm_steps, dim3(LBLK), dim3(512),
                               args, 0, stream);
  }

  // SEQ even -> final h written at s=511 (odd) into hA
  transpose_h<<<256, 256, 0, stream>>>((const u16*)hA, hT);
  phaseC<<<1000, 256, 0, stream>>>(hT, Wfc, bfc, out);
}